// Round 1
// baseline (107.208 us; speedup 1.0000x reference)
//
#include <hip/hip_runtime.h>

// loss = sum_{b,j} mean_{H,W}((out-tgt)^2) / B * W  with B=64, H=W=256, W(weight)=1
// == sum over ALL elements of diff^2  *  1/(H*W*B)
//
// Two-pass deterministic reduction:
//   pass 1: grid-stride float4 loads -> per-thread acc -> wave64 shuffle reduce
//           -> per-block LDS reduce -> partial[block] in d_ws
//   pass 2: one block reduces the partials, applies scale, writes d_out[0]

#define BLOCKS 2048
#define THREADS 256

__global__ __launch_bounds__(THREADS) void mse_partial_kernel(
    const float* __restrict__ a, const float* __restrict__ b,
    float* __restrict__ partial, int n4) {
    const float4* __restrict__ a4 = (const float4*)a;
    const float4* __restrict__ b4 = (const float4*)b;

    int idx = blockIdx.x * THREADS + threadIdx.x;
    int stride = gridDim.x * THREADS;

    float acc = 0.0f;
    for (int i = idx; i < n4; i += stride) {
        float4 x = a4[i];
        float4 y = b4[i];
        float d0 = x.x - y.x;
        float d1 = x.y - y.y;
        float d2 = x.z - y.z;
        float d3 = x.w - y.w;
        acc = fmaf(d0, d0, acc);
        acc = fmaf(d1, d1, acc);
        acc = fmaf(d2, d2, acc);
        acc = fmaf(d3, d3, acc);
    }

    // wave64 butterfly reduce
    #pragma unroll
    for (int off = 32; off >= 1; off >>= 1)
        acc += __shfl_down(acc, off, 64);

    __shared__ float wsum[THREADS / 64];
    int lane = threadIdx.x & 63;
    int wid = threadIdx.x >> 6;
    if (lane == 0) wsum[wid] = acc;
    __syncthreads();

    if (threadIdx.x == 0) {
        float s = 0.0f;
        #pragma unroll
        for (int w = 0; w < THREADS / 64; ++w) s += wsum[w];
        partial[blockIdx.x] = s;
    }
}

__global__ __launch_bounds__(THREADS) void mse_final_kernel(
    const float* __restrict__ partial, float* __restrict__ out,
    int nb, float scale) {
    float acc = 0.0f;
    for (int i = threadIdx.x; i < nb; i += THREADS) acc += partial[i];

    #pragma unroll
    for (int off = 32; off >= 1; off >>= 1)
        acc += __shfl_down(acc, off, 64);

    __shared__ float wsum[THREADS / 64];
    int lane = threadIdx.x & 63;
    int wid = threadIdx.x >> 6;
    if (lane == 0) wsum[wid] = acc;
    __syncthreads();

    if (threadIdx.x == 0) {
        float s = 0.0f;
        #pragma unroll
        for (int w = 0; w < THREADS / 64; ++w) s += wsum[w];
        out[0] = s * scale;
    }
}

extern "C" void kernel_launch(void* const* d_in, const int* in_sizes, int n_in,
                              void* d_out, int out_size, void* d_ws, size_t ws_size,
                              hipStream_t stream) {
    const float* a = (const float*)d_in[0];   // output [64,17,256,256] f32
    const float* b = (const float*)d_in[1];   // target [64,17,256,256] f32
    float* out = (float*)d_out;
    float* partial = (float*)d_ws;            // BLOCKS floats

    int n = in_sizes[0];                      // 71,303,168 (divisible by 4)
    int n4 = n >> 2;

    // scale = WEIGHT / (H*W) / B = 1 / (256*256*64)
    const float scale = 1.0f / (256.0f * 256.0f * 64.0f);

    mse_partial_kernel<<<BLOCKS, THREADS, 0, stream>>>(a, b, partial, n4);
    mse_final_kernel<<<1, THREADS, 0, stream>>>(partial, out, BLOCKS, scale);
}

// Round 3
// 89.564 us; speedup vs baseline: 1.1970x; 1.1970x over previous
//
#include <hip/hip_runtime.h>

// loss = sum_all (out-tgt)^2 / (H*W*B),  B=64,H=W=256, weight=1
//
// Pass 1: blocks x 256 threads, each thread exactly 32 float4 pairs
//         (block-contiguous 512KB segments), nontemporal loads, unroll 8,
//         wave64 shuffle reduce -> LDS -> partial[block] in d_ws.
// Pass 2: 1 block folds partials (+ any tail elements), scales, writes d_out.

#define THREADS 256
#define PER_THREAD 32   // float4 per thread in pass 1

using f4 = __attribute__((ext_vector_type(4))) float;  // nontemporal-compatible

__global__ __launch_bounds__(THREADS) void mse_partial_kernel(
    const f4* __restrict__ a4, const f4* __restrict__ b4,
    float* __restrict__ partial) {
    int base = blockIdx.x * (THREADS * PER_THREAD) + threadIdx.x;

    float acc = 0.0f;
    #pragma unroll 8
    for (int k = 0; k < PER_THREAD; ++k) {
        f4 x = __builtin_nontemporal_load(&a4[base + k * THREADS]);
        f4 y = __builtin_nontemporal_load(&b4[base + k * THREADS]);
        f4 d = x - y;
        acc = fmaf(d.x, d.x, acc);
        acc = fmaf(d.y, d.y, acc);
        acc = fmaf(d.z, d.z, acc);
        acc = fmaf(d.w, d.w, acc);
    }

    // wave64 butterfly reduce
    #pragma unroll
    for (int off = 32; off >= 1; off >>= 1)
        acc += __shfl_down(acc, off, 64);

    __shared__ float wsum[THREADS / 64];
    int lane = threadIdx.x & 63;
    int wid = threadIdx.x >> 6;
    if (lane == 0) wsum[wid] = acc;
    __syncthreads();

    if (threadIdx.x == 0) {
        float s = 0.0f;
        #pragma unroll
        for (int w = 0; w < THREADS / 64; ++w) s += wsum[w];
        partial[blockIdx.x] = s;
    }
}

// Folds per-block partials AND any tail elements [tail_start, n) not covered
// by pass 1 (tail is 0 for the benchmark shape; kept for generality).
__global__ __launch_bounds__(THREADS) void mse_final_kernel(
    const float* __restrict__ partial, int nb,
    const float* __restrict__ a, const float* __restrict__ b,
    int tail_start, int n,
    float* __restrict__ out, float scale) {
    float acc = 0.0f;
    for (int i = threadIdx.x; i < nb; i += THREADS) acc += partial[i];
    for (int i = tail_start + threadIdx.x; i < n; i += THREADS) {
        float d = a[i] - b[i];
        acc = fmaf(d, d, acc);
    }

    #pragma unroll
    for (int off = 32; off >= 1; off >>= 1)
        acc += __shfl_down(acc, off, 64);

    __shared__ float wsum[THREADS / 64];
    int lane = threadIdx.x & 63;
    int wid = threadIdx.x >> 6;
    if (lane == 0) wsum[wid] = acc;
    __syncthreads();

    if (threadIdx.x == 0) {
        float s = 0.0f;
        #pragma unroll
        for (int w = 0; w < THREADS / 64; ++w) s += wsum[w];
        out[0] = s * scale;
    }
}

extern "C" void kernel_launch(void* const* d_in, const int* in_sizes, int n_in,
                              void* d_out, int out_size, void* d_ws, size_t ws_size,
                              hipStream_t stream) {
    const float* a = (const float*)d_in[0];   // output [64,17,256,256] f32
    const float* b = (const float*)d_in[1];   // target [64,17,256,256] f32
    float* out = (float*)d_out;
    float* partial = (float*)d_ws;

    int n = in_sizes[0];                      // 71,303,168
    int n4 = n >> 2;                          // 17,825,792 float4 pairs
    int per_block = THREADS * PER_THREAD;     // 8192 float4 per block
    int blocks = n4 / per_block;              // 2176 (exact for this shape)
    int tail_start = blocks * per_block * 4;  // first scalar element not covered

    const float scale = 1.0f / (256.0f * 256.0f * 64.0f);

    mse_partial_kernel<<<blocks, THREADS, 0, stream>>>(
        (const f4*)a, (const f4*)b, partial);
    mse_final_kernel<<<1, THREADS, 0, stream>>>(
        partial, blocks, a, b, tail_start, n, out, scale);
}